// Round 5
// baseline (458.457 us; speedup 1.0000x reference)
//
#include <hip/hip_runtime.h>
#include <stdint.h>

// Net_49177375539428: recursive tree-NN scorer, all-fp32.
//   k_base : base[n,:] = vecs[data[n]] @ Wd + bd ; d_score at n==pos.
//   k_tree : LEVEL-WAVEFRONT sweep (tree height ~13, not 128 serial steps).
//            Per level, 4 waves process ready nodes in parallel (wave-gemv,
//            LDS float atomicAdd into parent row). Round-r reads touch only
//            lvl-r rows, writes touch lvl>=r+1 rows -> no read/write overlap.
//   k_chain: 256 blocks (8 graphs x 32 chunks of 4 edge-types); shared path
//            steps load W once per block, reused across the 4 e-rows.

#define NND 128
#define DD  128
#define GG  8
#define VD  300
#define CH  4          // e's per k_chain block

typedef unsigned int u32;

// desc bit layout: [0:6] par  [7:14] edge  [15] RELU  [16] POS  [17] PATH
//                  [18:24] lvl  [25:31] path slot
#define F_RELU (1u<<15)
#define F_POS  (1u<<16)
#define F_PATH (1u<<17)

// ---------------- K1: base embeddings + d_score ----------------
__global__ void __launch_bounds__(128) k_base(
        const int* __restrict__ data, const int* __restrict__ posArr,
        const float* __restrict__ vecs, const float* __restrict__ dw,
        const float* __restrict__ db,   const float* __restrict__ sdw,
        const float* __restrict__ sb,
        float* __restrict__ base, float* __restrict__ dscore)
{
    __shared__ __align__(16) float row[VD];
    __shared__ float red[DD];
    int n = blockIdx.x, t = threadIdx.x;
    int id = data[n];
    const float4* vp = (const float4*)(vecs + (size_t)id * VD);  // 1200B rows
    for (int i = t; i < VD/4; i += 128) ((float4*)row)[i] = vp[i];
    __syncthreads();
    float acc = db[t];
    for (int d = 0; d < VD; ++d)
        acc = fmaf(row[d], dw[d*DD + t], acc);
    base[n*DD + t] = acc;
    if (n == posArr[0]){
        red[t] = acc * sdw[t];
        __syncthreads();
        for (int o = 64; o > 0; o >>= 1){ if (t < o) red[t] += red[t+o]; __syncthreads(); }
        if (t == 0) dscore[0] = sb[0] + red[0];
    }
}

// ---------------- K2: level-wavefront tree sweep ----------------
// LDS: 127 acc rows (node r+1; node 0 is always a leaf -> src from base) +
// 128 descriptors = 127*512 + 512 = 65536 B exactly.
__global__ void __launch_bounds__(256, 1) k_tree(
        const int* __restrict__ graphs, const int* __restrict__ edges,
        const int* __restrict__ posArr, const float* __restrict__ EW,
        const float* __restrict__ EB,   const float* __restrict__ base,
        float* __restrict__ vposG, float* __restrict__ uG, int* __restrict__ meta)
{
    __shared__ __align__(16) float accL[NND-1][DD];
    __shared__ u32 desc[NND];
    int g = blockIdx.x, t = threadIdx.x;
    int l = t & 63, w = t >> 6;

    for (int idx = t; idx < (NND-1)*DD/4; idx += 256)
        ((float4*)accL)[idx] = ((const float4*)(base + DD))[idx];
    if (t < NND){
        int par = (t < NND-1) ? (t + graphs[g*NND + t]) : 0;
        desc[t] = (u32)par | ((u32)edges[t] << 7);
    }
    __syncthreads();
    if (t == 0){
        int p = posArr[0];
        desc[p] |= F_POS;
        // path walk pos -> root
        {
            int c = (int)(desc[p] & 0x7F), s = 0;
            for (;;){
                desc[c] |= F_PATH | ((u32)s << 25);
                meta[g*(NND+1) + 1 + s] = c;
                ++s;
                if (c == NND-1) break;
                c = (int)(desc[c] & 0x7F);
            }
            meta[g*(NND+1)] = s;     // path length L
        }
        // relu flags + levels (ascending pass: children of i are all < i)
        int mx = 0;
        for (int i = 0; i < NND-1; ++i){
            u32 d = desc[i];
            int pp = (int)(d & 0x7F);
            desc[pp] |= F_RELU;                       // i is a child of pp
            if (d & (F_POS | F_PATH)) continue;       // not transformed here
            int lv = (int)((d >> 18) & 0x7F);
            if (lv > mx) mx = lv;
            u32 dp = desc[pp];
            int lp = (int)((dp >> 18) & 0x7F);
            if (lv + 1 > lp)
                desc[pp] = (dp & ~(0x7Fu << 18)) | ((u32)(lv + 1) << 18);
        }
        // stash round count in root's (unused) par bits
        desc[NND-1] = (desc[NND-1] & ~0x7Fu) | (u32)(mx + 1);
    }
    __syncthreads();

    int nrounds = (int)(desc[NND-1] & 0x7F);
    int h  = l >> 5;          // d-half: rows h*64 .. h*64+63
    int c0 = 4 * (l & 31);    // output cols c0..c0+3
    int pos = posArr[0];

    for (int r = 0; r < nrounds; ++r){
        int m = 0;
        for (int i = 0; i < NND-1; ++i){
            u32 d = desc[i];                              // wave-uniform
            if (d & (F_POS | F_PATH)) continue;
            if ((int)((d >> 18) & 0x7F) != r) continue;
            if ((m++ & 3) != w) continue;                 // every-4th node per wave
            int par  = (int)(d & 0x7F);                   // par >= 1 always
            int e    = (int)((d >> 7) & 0xFF);
            bool rl  = (d & F_RELU) != 0;
            const float* Wp = EW + (size_t)e*(DD*DD) + (size_t)(h*64)*DD + c0;
            float s0=0.f, s1=0.f, s2=0.f, s3=0.f;
            if (i == 0){                                  // node 0: src = base row 0
                const float* sp = base + h*64;
                #pragma unroll 4
                for (int d4 = 0; d4 < 16; ++d4){
                    float4 av = *(const float4*)&sp[4*d4];
                    if (rl){ av.x=fmaxf(av.x,0.f); av.y=fmaxf(av.y,0.f);
                             av.z=fmaxf(av.z,0.f); av.w=fmaxf(av.w,0.f); }
                    float4 w0 = *(const float4*)&Wp[(4*d4+0)*DD];
                    float4 w1 = *(const float4*)&Wp[(4*d4+1)*DD];
                    float4 w2 = *(const float4*)&Wp[(4*d4+2)*DD];
                    float4 w3 = *(const float4*)&Wp[(4*d4+3)*DD];
                    s0=fmaf(av.x,w0.x,s0); s1=fmaf(av.x,w0.y,s1); s2=fmaf(av.x,w0.z,s2); s3=fmaf(av.x,w0.w,s3);
                    s0=fmaf(av.y,w1.x,s0); s1=fmaf(av.y,w1.y,s1); s2=fmaf(av.y,w1.z,s2); s3=fmaf(av.y,w1.w,s3);
                    s0=fmaf(av.z,w2.x,s0); s1=fmaf(av.z,w2.y,s1); s2=fmaf(av.z,w2.z,s2); s3=fmaf(av.z,w2.w,s3);
                    s0=fmaf(av.w,w3.x,s0); s1=fmaf(av.w,w3.y,s1); s2=fmaf(av.w,w3.z,s2); s3=fmaf(av.w,w3.w,s3);
                }
            } else {                                      // src = LDS acc row
                const float* sp = &accL[i-1][h*64];
                #pragma unroll 4
                for (int d4 = 0; d4 < 16; ++d4){
                    float4 av = *(const float4*)&sp[4*d4];
                    if (rl){ av.x=fmaxf(av.x,0.f); av.y=fmaxf(av.y,0.f);
                             av.z=fmaxf(av.z,0.f); av.w=fmaxf(av.w,0.f); }
                    float4 w0 = *(const float4*)&Wp[(4*d4+0)*DD];
                    float4 w1 = *(const float4*)&Wp[(4*d4+1)*DD];
                    float4 w2 = *(const float4*)&Wp[(4*d4+2)*DD];
                    float4 w3 = *(const float4*)&Wp[(4*d4+3)*DD];
                    s0=fmaf(av.x,w0.x,s0); s1=fmaf(av.x,w0.y,s1); s2=fmaf(av.x,w0.z,s2); s3=fmaf(av.x,w0.w,s3);
                    s0=fmaf(av.y,w1.x,s0); s1=fmaf(av.y,w1.y,s1); s2=fmaf(av.y,w1.z,s2); s3=fmaf(av.y,w1.w,s3);
                    s0=fmaf(av.z,w2.x,s0); s1=fmaf(av.z,w2.y,s1); s2=fmaf(av.z,w2.z,s2); s3=fmaf(av.z,w2.w,s3);
                    s0=fmaf(av.w,w3.x,s0); s1=fmaf(av.w,w3.y,s1); s2=fmaf(av.w,w3.z,s2); s3=fmaf(av.w,w3.w,s3);
                }
            }
            s0 += __shfl_xor(s0, 32); s1 += __shfl_xor(s1, 32);
            s2 += __shfl_xor(s2, 32); s3 += __shfl_xor(s3, 32);
            if (l < 32){
                float4 bb = *(const float4*)&EB[(size_t)e*DD + c0];
                atomicAdd(&accL[par-1][c0+0], s0 + bb.x);
                atomicAdd(&accL[par-1][c0+1], s1 + bb.y);
                atomicAdd(&accL[par-1][c0+2], s2 + bb.z);
                atomicAdd(&accL[par-1][c0+3], s3 + bb.w);
            }
        }
        __syncthreads();
    }

    // ---- final stores: vpos (post-relu) + path-node u's (pre-relu) ----
    if (t < DD){
        u32 dp = desc[pos];
        float v = (pos == 0) ? base[t] : accL[pos-1][t];
        if (dp & F_RELU) v = fmaxf(v, 0.f);
        vposG[g*DD + t] = v;
    }
    for (int i = 1; i < NND; ++i){
        u32 d = desc[i];
        if ((d & F_PATH) && t < DD){
            int s = (int)(d >> 25);
            uG[((size_t)g*NND + s)*DD + t] = accL[i-1][t];
        }
    }
}

// ---------------- K3: path chains, 4 edge-types per block ----------------
__global__ void __launch_bounds__(256, 1) k_chain(
        const int* __restrict__ edges,
        const float* __restrict__ EW, const float* __restrict__ EB,
        const float* __restrict__ SEW,
        const float* __restrict__ vposG, const float* __restrict__ uG,
        const int* __restrict__ meta, const float* __restrict__ dscore,
        float* __restrict__ outp)
{
    __shared__ __align__(16) float Vbuf[2][CH][DD];
    __shared__ float red[CH][4];
    int g = blockIdx.x >> 5, chunk = blockIdx.x & 31;
    int t = threadIdx.x, l = t & 63, w = t >> 6;
    int k4 = w*8 + (l & 7);
    int d0 = (l >> 3) * 16;
    bool owner = ((l >> 3) == 0);
    int eBase = chunk * CH;
    int L = meta[g*(NND+1)];

    float vpf[16];
    #pragma unroll
    for (int j = 0; j < 4; ++j){
        float4 x = *(const float4*)&vposG[g*DD + d0 + 4*j];
        vpf[4*j+0]=x.x; vpf[4*j+1]=x.y; vpf[4*j+2]=x.z; vpf[4*j+3]=x.w;
    }
    float4 u0 = *(const float4*)&uG[(size_t)g*NND*DD + 4*k4];

    // ---- step 0: per-e weights W[e] ----
    #pragma unroll 2
    for (int p = 0; p < CH; ++p){
        int e = eBase + p;
        const float* Wp = EW + (size_t)e*(DD*DD) + (size_t)d0*DD + 4*k4;
        float s0=0.f, s1=0.f, s2=0.f, s3=0.f;
        #pragma unroll
        for (int d = 0; d < 16; ++d){
            float4 wv = *(const float4*)&Wp[d*DD];
            s0 = fmaf(vpf[d], wv.x, s0);
            s1 = fmaf(vpf[d], wv.y, s1);
            s2 = fmaf(vpf[d], wv.z, s2);
            s3 = fmaf(vpf[d], wv.w, s3);
        }
        #pragma unroll
        for (int m = 8; m <= 32; m <<= 1){
            s0 += __shfl_xor(s0, m); s1 += __shfl_xor(s1, m);
            s2 += __shfl_xor(s2, m); s3 += __shfl_xor(s3, m);
        }
        if (owner){
            float4 bb = *(const float4*)&EB[(size_t)e*DD + 4*k4];
            float4 r;
            r.x = fmaxf(u0.x + s0 + bb.x, 0.f);
            r.y = fmaxf(u0.y + s1 + bb.y, 0.f);
            r.z = fmaxf(u0.z + s2 + bb.z, 0.f);
            r.w = fmaxf(u0.w + s3 + bb.w, 0.f);
            *(float4*)&Vbuf[0][p][4*k4] = r;
        }
    }
    __syncthreads();

    // ---- shared steps 1..L-1: one W per step, reused across CH e-rows ----
    int cur = 0;
    for (int s = 1; s < L; ++s){
        int pn = meta[g*(NND+1) + s];           // path[s-1]
        int ej = edges[pn];
        const float* Wp = EW + (size_t)ej*(DD*DD) + (size_t)d0*DD + 4*k4;
        float4 wr[16];
        #pragma unroll
        for (int d = 0; d < 16; ++d) wr[d] = *(const float4*)&Wp[d*DD];
        float4 us = *(const float4*)&uG[((size_t)g*NND + s)*DD + 4*k4];
        float4 bb = *(const float4*)&EB[(size_t)ej*DD + 4*k4];
        #pragma unroll
        for (int p = 0; p < CH; ++p){
            float ev[16];
            #pragma unroll
            for (int j = 0; j < 4; ++j){
                float4 x = *(const float4*)&Vbuf[cur][p][d0 + 4*j];
                ev[4*j+0]=x.x; ev[4*j+1]=x.y; ev[4*j+2]=x.z; ev[4*j+3]=x.w;
            }
            float s0=0.f, s1=0.f, s2=0.f, s3=0.f;
            #pragma unroll
            for (int d = 0; d < 16; ++d){
                s0 = fmaf(ev[d], wr[d].x, s0);
                s1 = fmaf(ev[d], wr[d].y, s1);
                s2 = fmaf(ev[d], wr[d].z, s2);
                s3 = fmaf(ev[d], wr[d].w, s3);
            }
            #pragma unroll
            for (int m = 8; m <= 32; m <<= 1){
                s0 += __shfl_xor(s0, m); s1 += __shfl_xor(s1, m);
                s2 += __shfl_xor(s2, m); s3 += __shfl_xor(s3, m);
            }
            if (owner){
                float4 r;
                r.x = fmaxf(us.x + s0 + bb.x, 0.f);
                r.y = fmaxf(us.y + s1 + bb.y, 0.f);
                r.z = fmaxf(us.z + s2 + bb.z, 0.f);
                r.w = fmaxf(us.w + s3 + bb.w, 0.f);
                *(float4*)&Vbuf[cur^1][p][4*k4] = r;
            }
        }
        __syncthreads();
        cur ^= 1;
    }

    // ---- final transform (root edge) + score ----
    {
        int rn = meta[g*(NND+1) + L];           // path[L-1] (= 127)
        int er = edges[rn];
        const float* Wp = EW + (size_t)er*(DD*DD) + (size_t)d0*DD + 4*k4;
        float4 wr[16];
        #pragma unroll
        for (int d = 0; d < 16; ++d) wr[d] = *(const float4*)&Wp[d*DD];
        float4 bb = *(const float4*)&EB[(size_t)er*DD + 4*k4];
        float4 sw = *(const float4*)&SEW[4*k4];
        #pragma unroll
        for (int p = 0; p < CH; ++p){
            float ev[16];
            #pragma unroll
            for (int j = 0; j < 4; ++j){
                float4 x = *(const float4*)&Vbuf[cur][p][d0 + 4*j];
                ev[4*j+0]=x.x; ev[4*j+1]=x.y; ev[4*j+2]=x.z; ev[4*j+3]=x.w;
            }
            float s0=0.f, s1=0.f, s2=0.f, s3=0.f;
            #pragma unroll
            for (int d = 0; d < 16; ++d){
                s0 = fmaf(ev[d], wr[d].x, s0);
                s1 = fmaf(ev[d], wr[d].y, s1);
                s2 = fmaf(ev[d], wr[d].z, s2);
                s3 = fmaf(ev[d], wr[d].w, s3);
            }
            #pragma unroll
            for (int m = 8; m <= 32; m <<= 1){
                s0 += __shfl_xor(s0, m); s1 += __shfl_xor(s1, m);
                s2 += __shfl_xor(s2, m); s3 += __shfl_xor(s3, m);
            }
            if (owner){
                float part = (s0 + bb.x) * sw.x + (s1 + bb.y) * sw.y
                           + (s2 + bb.z) * sw.z + (s3 + bb.w) * sw.w;
                part += __shfl_xor(part, 1);
                part += __shfl_xor(part, 2);
                part += __shfl_xor(part, 4);
                if (l == 0) red[p][w] = part;
            }
        }
        __syncthreads();
        if (t < CH)
            outp[g*DD + eBase + t] = dscore[0] + red[t][0] + red[t][1] + red[t][2] + red[t][3];
    }
}

extern "C" void kernel_launch(void* const* d_in, const int* in_sizes, int n_in,
                              void* d_out, int out_size, void* d_ws, size_t ws_size,
                              hipStream_t stream)
{
    const int*   data   = (const int*)d_in[0];
    /* d_in[1] = types, unused (single data_type) */
    const int*   graphs = (const int*)d_in[2];
    const int*   edges  = (const int*)d_in[3];
    const int*   posArr = (const int*)d_in[4];
    const float* vecs   = (const float*)d_in[5];
    const float* dw     = (const float*)d_in[6];
    const float* db     = (const float*)d_in[7];
    const float* ew     = (const float*)d_in[8];
    const float* eb     = (const float*)d_in[9];
    const float* sew    = (const float*)d_in[10];
    const float* sdw    = (const float*)d_in[11];
    const float* sb     = (const float*)d_in[12];

    char* ws = (char*)d_ws;
    float* base   = (float*)(ws);                               // 64 KB
    float* vposG  = (float*)(ws + 65536);                       // 4 KB
    float* uG     = (float*)(ws + 65536 + 4096);                // 512 KB
    float* dscore = (float*)(ws + 65536 + 4096 + 524288);       // 1 f32
    int*   meta   = (int*)  (ws + 65536 + 4096 + 524288 + 256); // 8*129 ints

    float* outp = (float*)d_out;

    k_base <<<NND, 128, 0, stream>>>(data, posArr, vecs, dw, db, sdw, sb, base, dscore);
    k_tree <<<GG, 256, 0, stream>>>(graphs, edges, posArr, ew, eb, base, vposG, uG, meta);
    k_chain<<<GG*(DD/CH), 256, 0, stream>>>(edges, ew, eb, sew, vposG, uG, meta, dscore, outp);
}

// Round 6
// 378.635 us; speedup vs baseline: 1.2108x; 1.2108x over previous
//
#include <hip/hip_runtime.h>
#include <stdint.h>

// Net_49177375539428: recursive tree-NN scorer, all-fp32.
//   k_base : base[n,:] = vecs[data[n]] @ Wd + bd ; d_score at n==pos.
//   k_tree : strict index-order sweep over a compacted list of regular nodes.
//            512 threads; per step the whole block loads W[e] once (8 float4
//            per lane), register double-buffer prefetches step j+2, one
//            LDS-only barrier per step (prefetch stays in flight).
//            Wave w owns output cols [16w,16w+16) exclusively -> plain RMW.
//   k_chain: 256 blocks (8 graphs x 32 chunks of 4 edge-types); shared path
//            steps load W once per block, reused across the 4 e-rows.

#define NND 128
#define DD  128
#define GG  8
#define VD  300
#define CH  4

typedef unsigned int u32;

// LDS-only barrier: waits ds ops, leaves global (prefetch) loads in flight.
#define SYNC_LDS() asm volatile("s_waitcnt lgkmcnt(0)\n\ts_barrier" ::: "memory")

// ---------------- K1: base embeddings + d_score ----------------
__global__ void __launch_bounds__(128) k_base(
        const int* __restrict__ data, const int* __restrict__ posArr,
        const float* __restrict__ vecs, const float* __restrict__ dw,
        const float* __restrict__ db,   const float* __restrict__ sdw,
        const float* __restrict__ sb,
        float* __restrict__ base, float* __restrict__ dscore)
{
    __shared__ __align__(16) float row[VD];
    __shared__ float red[DD];
    int n = blockIdx.x, t = threadIdx.x;
    int id = data[n];
    const float4* vp = (const float4*)(vecs + (size_t)id * VD);  // 1200B rows
    for (int i = t; i < VD/4; i += 128) ((float4*)row)[i] = vp[i];
    __syncthreads();
    float acc = db[t];
    #pragma unroll 5
    for (int d4 = 0; d4 < VD/4; ++d4){
        float4 r = *(const float4*)&row[4*d4];
        acc = fmaf(r.x, dw[(4*d4+0)*DD + t], acc);
        acc = fmaf(r.y, dw[(4*d4+1)*DD + t], acc);
        acc = fmaf(r.z, dw[(4*d4+2)*DD + t], acc);
        acc = fmaf(r.w, dw[(4*d4+3)*DD + t], acc);
    }
    base[n*DD + t] = acc;
    if (n == posArr[0]){
        red[t] = acc * sdw[t];
        __syncthreads();
        for (int o = 64; o > 0; o >>= 1){ if (t < o) red[t] += red[t+o]; __syncthreads(); }
        if (t == 0) dscore[0] = sb[0] + red[0];
    }
}

// ---------------- K2: pipelined index-order sweep ----------------
// sinfo word: [0:7] src node  [8:15] parent (128 = trash row)  [16] relu
//             [17:23] edge
__global__ void __launch_bounds__(512, 2) k_tree(
        const int* __restrict__ graphs, const int* __restrict__ edges,
        const int* __restrict__ posArr, const float* __restrict__ EW,
        const float* __restrict__ EB,   const float* __restrict__ base,
        float* __restrict__ vposG, float* __restrict__ uG, int* __restrict__ meta)
{
    __shared__ __align__(16) float accL[NND+1][DD];   // row 128 = trash
    __shared__ u32 nfo[NND];      // [0:7] par, bit8 = haschild, bit9 = onpath
    __shared__ u32 sinfo[NND];
    __shared__ int pathL[NND];
    __shared__ int ctl[2];        // L, nst
    int g = blockIdx.x, t = threadIdx.x;
    int l = t & 63, w = t >> 6;   // 8 waves

    for (int idx = t; idx < NND*DD/4; idx += 512)
        ((float4*)accL)[idx] = ((const float4*)base)[idx];
    if (t < NND)
        nfo[t] = (t < NND-1) ? (u32)(t + graphs[g*NND + t]) : 0xFFu;
    __syncthreads();
    if (t < NND-1) atomicOr(&nfo[nfo[t] & 0xFFu], 0x100u);
    __syncthreads();
    int pos = posArr[0];
    if (t == 0){
        int c = (int)(nfo[pos] & 0xFFu), s = 0;
        for (;;){
            nfo[c] |= 0x200u;
            pathL[s] = c;
            ++s;
            if (c == NND-1) break;
            c = (int)(nfo[c] & 0xFFu);
        }
        ctl[0] = s;
        meta[g*(NND+1)] = s;
        for (int q = 0; q < s; ++q) meta[g*(NND+1) + 1 + q] = pathL[q];
        int m = 0;
        for (int i = 0; i < NND-1; ++i){
            u32 nf = nfo[i];
            if (i == pos || (nf & 0x200u)) continue;
            sinfo[m++] = (u32)i | ((nf & 0xFFu) << 8)
                       | ((nf & 0x100u) ? 0x10000u : 0u)
                       | ((u32)edges[i] << 17);
        }
        if (m & 1) sinfo[m++] = (128u << 8);   // pad: src 0 -> trash row
        ctl[1] = m;
    }
    __syncthreads();
    int nst = ctl[1];

    int cbase = 16*w + 4*(l & 3);   // this lane's 4 output cols
    int dg = l >> 2;                // 0..15 -> d-range [8dg, 8dg+8)

    auto PF = [&](u32 si, float4 (&W)[8], float4& bb){
        int e = (int)((si >> 17) & 0x7Fu);
        const float* Wp = EW + (size_t)e*(DD*DD) + (size_t)(8*dg)*DD + cbase;
        #pragma unroll
        for (int k = 0; k < 8; ++k) W[k] = *(const float4*)(Wp + k*DD);
        bb = *(const float4*)&EB[(size_t)e*DD + cbase];
    };
    auto STEP = [&](u32 si, const float4 (&W)[8], const float4& bb){
        int n   = (int)(si & 0xFFu);
        int par = (int)((si >> 8) & 0xFFu);
        float4 sa = *(const float4*)&accL[n][8*dg];
        float4 sbv = *(const float4*)&accL[n][8*dg + 4];
        if (si & 0x10000u){
            sa.x=fmaxf(sa.x,0.f); sa.y=fmaxf(sa.y,0.f);
            sa.z=fmaxf(sa.z,0.f); sa.w=fmaxf(sa.w,0.f);
            sbv.x=fmaxf(sbv.x,0.f); sbv.y=fmaxf(sbv.y,0.f);
            sbv.z=fmaxf(sbv.z,0.f); sbv.w=fmaxf(sbv.w,0.f);
        }
        float s0, s1, s2, s3;
        s0 = sa.x*W[0].x; s1 = sa.x*W[0].y; s2 = sa.x*W[0].z; s3 = sa.x*W[0].w;
        s0 = fmaf(sa.y,W[1].x,s0); s1 = fmaf(sa.y,W[1].y,s1); s2 = fmaf(sa.y,W[1].z,s2); s3 = fmaf(sa.y,W[1].w,s3);
        s0 = fmaf(sa.z,W[2].x,s0); s1 = fmaf(sa.z,W[2].y,s1); s2 = fmaf(sa.z,W[2].z,s2); s3 = fmaf(sa.z,W[2].w,s3);
        s0 = fmaf(sa.w,W[3].x,s0); s1 = fmaf(sa.w,W[3].y,s1); s2 = fmaf(sa.w,W[3].z,s2); s3 = fmaf(sa.w,W[3].w,s3);
        s0 = fmaf(sbv.x,W[4].x,s0); s1 = fmaf(sbv.x,W[4].y,s1); s2 = fmaf(sbv.x,W[4].z,s2); s3 = fmaf(sbv.x,W[4].w,s3);
        s0 = fmaf(sbv.y,W[5].x,s0); s1 = fmaf(sbv.y,W[5].y,s1); s2 = fmaf(sbv.y,W[5].z,s2); s3 = fmaf(sbv.y,W[5].w,s3);
        s0 = fmaf(sbv.z,W[6].x,s0); s1 = fmaf(sbv.z,W[6].y,s1); s2 = fmaf(sbv.z,W[6].z,s2); s3 = fmaf(sbv.z,W[6].w,s3);
        s0 = fmaf(sbv.w,W[7].x,s0); s1 = fmaf(sbv.w,W[7].y,s1); s2 = fmaf(sbv.w,W[7].z,s2); s3 = fmaf(sbv.w,W[7].w,s3);
        #pragma unroll
        for (int mm = 4; mm <= 32; mm <<= 1){
            s0 += __shfl_xor(s0, mm); s1 += __shfl_xor(s1, mm);
            s2 += __shfl_xor(s2, mm); s3 += __shfl_xor(s3, mm);
        }
        if (l < 4){                              // unique cols per wave
            float4* dst = (float4*)&accL[par][cbase];
            float4 o = *dst;
            o.x += s0 + bb.x; o.y += s1 + bb.y;
            o.z += s2 + bb.z; o.w += s3 + bb.w;
            *dst = o;
        }
    };

    u32 siA = sinfo[0], siB = sinfo[1];
    float4 WA[8], WB[8], bbA, bbB;
    PF(siA, WA, bbA);
    PF(siB, WB, bbB);
    for (int j = 0; j < nst; j += 2){
        STEP(siA, WA, bbA);
        if (j + 2 < nst){ siA = sinfo[j+2]; PF(siA, WA, bbA); }
        SYNC_LDS();
        STEP(siB, WB, bbB);
        if (j + 3 < nst){ siB = sinfo[j+3]; PF(siB, WB, bbB); }
        SYNC_LDS();
    }

    // ---- final stores: vpos (post-relu) + path-node u's (pre-relu) ----
    if (t < DD){
        float v = accL[pos][t];
        if (nfo[pos] & 0x100u) v = fmaxf(v, 0.f);
        vposG[g*DD + t] = v;
        int L = ctl[0];
        for (int s = 0; s < L; ++s)
            uG[((size_t)g*NND + s)*DD + t] = accL[pathL[s]][t];
    }
}

// ---------------- K3: path chains, 4 edge-types per block ----------------
__global__ void __launch_bounds__(256, 1) k_chain(
        const int* __restrict__ edges,
        const float* __restrict__ EW, const float* __restrict__ EB,
        const float* __restrict__ SEW,
        const float* __restrict__ vposG, const float* __restrict__ uG,
        const int* __restrict__ meta, const float* __restrict__ dscore,
        float* __restrict__ outp)
{
    __shared__ __align__(16) float Vbuf[2][CH][DD];
    __shared__ float red[CH][4];
    int g = blockIdx.x >> 5, chunk = blockIdx.x & 31;
    int t = threadIdx.x, l = t & 63, w = t >> 6;
    int k4 = w*8 + (l & 7);
    int d0 = (l >> 3) * 16;
    bool owner = ((l >> 3) == 0);
    int eBase = chunk * CH;
    int L = meta[g*(NND+1)];

    float vpf[16];
    #pragma unroll
    for (int j = 0; j < 4; ++j){
        float4 x = *(const float4*)&vposG[g*DD + d0 + 4*j];
        vpf[4*j+0]=x.x; vpf[4*j+1]=x.y; vpf[4*j+2]=x.z; vpf[4*j+3]=x.w;
    }
    float4 u0 = *(const float4*)&uG[(size_t)g*NND*DD + 4*k4];

    // ---- step 0: per-e weights W[e] ----
    #pragma unroll 2
    for (int p = 0; p < CH; ++p){
        int e = eBase + p;
        const float* Wp = EW + (size_t)e*(DD*DD) + (size_t)d0*DD + 4*k4;
        float s0=0.f, s1=0.f, s2=0.f, s3=0.f;
        #pragma unroll
        for (int d = 0; d < 16; ++d){
            float4 wv = *(const float4*)&Wp[d*DD];
            s0 = fmaf(vpf[d], wv.x, s0);
            s1 = fmaf(vpf[d], wv.y, s1);
            s2 = fmaf(vpf[d], wv.z, s2);
            s3 = fmaf(vpf[d], wv.w, s3);
        }
        #pragma unroll
        for (int m = 8; m <= 32; m <<= 1){
            s0 += __shfl_xor(s0, m); s1 += __shfl_xor(s1, m);
            s2 += __shfl_xor(s2, m); s3 += __shfl_xor(s3, m);
        }
        if (owner){
            float4 bb = *(const float4*)&EB[(size_t)e*DD + 4*k4];
            float4 r;
            r.x = fmaxf(u0.x + s0 + bb.x, 0.f);
            r.y = fmaxf(u0.y + s1 + bb.y, 0.f);
            r.z = fmaxf(u0.z + s2 + bb.z, 0.f);
            r.w = fmaxf(u0.w + s3 + bb.w, 0.f);
            *(float4*)&Vbuf[0][p][4*k4] = r;
        }
    }
    __syncthreads();

    // ---- shared steps 1..L-1: one W per step, reused across CH e-rows ----
    int cur = 0;
    for (int s = 1; s < L; ++s){
        int pn = meta[g*(NND+1) + s];           // path[s-1]
        int ej = edges[pn];
        const float* Wp = EW + (size_t)ej*(DD*DD) + (size_t)d0*DD + 4*k4;
        float4 wr[16];
        #pragma unroll
        for (int d = 0; d < 16; ++d) wr[d] = *(const float4*)&Wp[d*DD];
        float4 us = *(const float4*)&uG[((size_t)g*NND + s)*DD + 4*k4];
        float4 bb = *(const float4*)&EB[(size_t)ej*DD + 4*k4];
        #pragma unroll
        for (int p = 0; p < CH; ++p){
            float ev[16];
            #pragma unroll
            for (int j = 0; j < 4; ++j){
                float4 x = *(const float4*)&Vbuf[cur][p][d0 + 4*j];
                ev[4*j+0]=x.x; ev[4*j+1]=x.y; ev[4*j+2]=x.z; ev[4*j+3]=x.w;
            }
            float s0=0.f, s1=0.f, s2=0.f, s3=0.f;
            #pragma unroll
            for (int d = 0; d < 16; ++d){
                s0 = fmaf(ev[d], wr[d].x, s0);
                s1 = fmaf(ev[d], wr[d].y, s1);
                s2 = fmaf(ev[d], wr[d].z, s2);
                s3 = fmaf(ev[d], wr[d].w, s3);
            }
            #pragma unroll
            for (int m = 8; m <= 32; m <<= 1){
                s0 += __shfl_xor(s0, m); s1 += __shfl_xor(s1, m);
                s2 += __shfl_xor(s2, m); s3 += __shfl_xor(s3, m);
            }
            if (owner){
                float4 r;
                r.x = fmaxf(us.x + s0 + bb.x, 0.f);
                r.y = fmaxf(us.y + s1 + bb.y, 0.f);
                r.z = fmaxf(us.z + s2 + bb.z, 0.f);
                r.w = fmaxf(us.w + s3 + bb.w, 0.f);
                *(float4*)&Vbuf[cur^1][p][4*k4] = r;
            }
        }
        __syncthreads();
        cur ^= 1;
    }

    // ---- final transform (root edge) + score ----
    {
        int rn = meta[g*(NND+1) + L];           // path[L-1] (= 127)
        int er = edges[rn];
        const float* Wp = EW + (size_t)er*(DD*DD) + (size_t)d0*DD + 4*k4;
        float4 wr[16];
        #pragma unroll
        for (int d = 0; d < 16; ++d) wr[d] = *(const float4*)&Wp[d*DD];
        float4 bb = *(const float4*)&EB[(size_t)er*DD + 4*k4];
        float4 sw = *(const float4*)&SEW[4*k4];
        #pragma unroll
        for (int p = 0; p < CH; ++p){
            float ev[16];
            #pragma unroll
            for (int j = 0; j < 4; ++j){
                float4 x = *(const float4*)&Vbuf[cur][p][d0 + 4*j];
                ev[4*j+0]=x.x; ev[4*j+1]=x.y; ev[4*j+2]=x.z; ev[4*j+3]=x.w;
            }
            float s0=0.f, s1=0.f, s2=0.f, s3=0.f;
            #pragma unroll
            for (int d = 0; d < 16; ++d){
                s0 = fmaf(ev[d], wr[d].x, s0);
                s1 = fmaf(ev[d], wr[d].y, s1);
                s2 = fmaf(ev[d], wr[d].z, s2);
                s3 = fmaf(ev[d], wr[d].w, s3);
            }
            #pragma unroll
            for (int m = 8; m <= 32; m <<= 1){
                s0 += __shfl_xor(s0, m); s1 += __shfl_xor(s1, m);
                s2 += __shfl_xor(s2, m); s3 += __shfl_xor(s3, m);
            }
            if (owner){
                float part = (s0 + bb.x) * sw.x + (s1 + bb.y) * sw.y
                           + (s2 + bb.z) * sw.z + (s3 + bb.w) * sw.w;
                part += __shfl_xor(part, 1);
                part += __shfl_xor(part, 2);
                part += __shfl_xor(part, 4);
                if (l == 0) red[p][w] = part;
            }
        }
        __syncthreads();
        if (t < CH)
            outp[g*DD + eBase + t] = dscore[0] + red[t][0] + red[t][1] + red[t][2] + red[t][3];
    }
}

extern "C" void kernel_launch(void* const* d_in, const int* in_sizes, int n_in,
                              void* d_out, int out_size, void* d_ws, size_t ws_size,
                              hipStream_t stream)
{
    const int*   data   = (const int*)d_in[0];
    /* d_in[1] = types, unused (single data_type) */
    const int*   graphs = (const int*)d_in[2];
    const int*   edges  = (const int*)d_in[3];
    const int*   posArr = (const int*)d_in[4];
    const float* vecs   = (const float*)d_in[5];
    const float* dw     = (const float*)d_in[6];
    const float* db     = (const float*)d_in[7];
    const float* ew     = (const float*)d_in[8];
    const float* eb     = (const float*)d_in[9];
    const float* sew    = (const float*)d_in[10];
    const float* sdw    = (const float*)d_in[11];
    const float* sb     = (const float*)d_in[12];

    char* ws = (char*)d_ws;
    float* base   = (float*)(ws);                               // 64 KB
    float* vposG  = (float*)(ws + 65536);                       // 4 KB
    float* uG     = (float*)(ws + 65536 + 4096);                // 512 KB
    float* dscore = (float*)(ws + 65536 + 4096 + 524288);       // 1 f32
    int*   meta   = (int*)  (ws + 65536 + 4096 + 524288 + 256); // 8*129 ints

    float* outp = (float*)d_out;

    k_base <<<NND, 128, 0, stream>>>(data, posArr, vecs, dw, db, sdw, sb, base, dscore);
    k_tree <<<GG, 512, 0, stream>>>(graphs, edges, posArr, ew, eb, base, vposG, uG, meta);
    k_chain<<<GG*(DD/CH), 256, 0, stream>>>(edges, ew, eb, sew, vposG, uG, meta, dscore, outp);
}